// Round 15
// baseline (36.190 us; speedup 1.0000x reference)
//
#include <hip/hip_runtime.h>
#include <stdint.h>

typedef __attribute__((ext_vector_type(8))) short short8;
typedef __attribute__((ext_vector_type(4))) float f32x4;
typedef __attribute__((ext_vector_type(16))) float f32x16;
typedef __attribute__((ext_vector_type(4))) unsigned int u32x4;

#define NE 500000
#define NN 50000
#define NT32 1563            // ceil(50000/32); last tile has 16 real nodes
#define SC_BLOCKS 2048
#define SC_THREADS (SC_BLOCKS * 256)

__device__ __forceinline__ unsigned int f2bf1(float f) {
  unsigned int u = __builtin_bit_cast(unsigned int, f);
  u += 0x7FFFu + ((u >> 16) & 1u);   // round-to-nearest-even
  return u >> 16;
}
__device__ __forceinline__ unsigned int packbf2(float lo, float hi) {
  return f2bf1(lo) | (f2bf1(hi) << 16);
}
__device__ __forceinline__ short8 pack8(f32x4 a, f32x4 b) {
  short8 r;
  r[0] = (short)f2bf1(a[0]); r[1] = (short)f2bf1(a[1]);
  r[2] = (short)f2bf1(a[2]); r[3] = (short)f2bf1(a[3]);
  r[4] = (short)f2bf1(b[0]); r[5] = (short)f2bf1(b[1]);
  r[6] = (short)f2bf1(b[2]); r[7] = (short)f2bf1(b[3]);
  return r;
}

// direct global->LDS DMA, 16B per lane (dest = wave-uniform base + lane*16)
__device__ __forceinline__ void gl2lds16(const void* g, void* l) {
  __builtin_amdgcn_global_load_lds(
      (const __attribute__((address_space(1))) void*)g,
      (__attribute__((address_space(3))) void*)l, 16, 0, 0);
}

// ---------------------------------------------------------------------------
// Prep: pack W1..W4 (f32) into kappa-ordered bf16 fragments (R10 layout).
// ---------------------------------------------------------------------------
__global__ __launch_bounds__(256) void prep_weights(
    const float* __restrict__ W1, const float* __restrict__ W2,
    const float* __restrict__ W3, const float* __restrict__ W4,
    unsigned short* __restrict__ wf) {
  int idx = blockIdx.x * 256 + threadIdx.x;   // 8704 tasks = 34 blocks
  if (idx >= 8704) return;
  int f = idx >> 6, l = idx & 63;
  int r = l & 31, hh = l >> 5;
  const float *pa, *pb;
  if (f < 8) {
    int ob = f >> 1, s = f & 1;
    const float* base = W1 + (ob * 32 + r) * 32 + s * 16 + hh * 8;
    pa = base; pb = base + 4;
  } else {
    const float* W; int i2;
    if (f < 40)      { W = W2; i2 = f - 8;  }
    else if (f < 72) { W = W3; i2 = f - 40; }
    else             { W = W4; i2 = f - 72; }
    int ob = i2 >> 3, s = i2 & 7;
    const float* base = W + (ob * 32 + r) * 128
                      + (s >> 1) * 32 + (s & 1) * 16 + 4 * hh;
    pa = base; pb = base + 8;
  }
  *(short8*)&wf[f * 512 + l * 8] = pack8(*(const f32x4*)pa, *(const f32x4*)pb);
}

// ---------------------------------------------------------------------------
// MLP (R10 math): 512 thr = 8 waves, one 32-node tile/wave.
// NEW vs R14:
//  * counted-vmcnt pipelined staging: DMA rounds ordered by layer
//    (round 0 = W1 frags 0-7; 1-4 = W2; 5-8 = W3; 9-16 = W4); each layer is
//    gated by s_waitcnt vmcnt(16/12/8/0) + raw s_barrier, so W2..W4 DMA
//    flies under L1..L3 compute (no monolithic vmcnt(0) drain).
//  * rolled L2/L3 layer loop + rolled L4 nb4 loop (inner 8-step s loops stay
//    unrolled): ~4x smaller code -> kills per-replay I$ cold-miss serial cost.
//  Issue order: bias load (oldest), ef/nf loads, then 17 DMAs -> compiler's
//  own waits for bias/ef retire cheaply without draining the DMA queue.
// ---------------------------------------------------------------------------
__global__ __launch_bounds__(512, 2) void mlp_kernel(
    const float* __restrict__ ef, const float* __restrict__ nfeat,
    const float* __restrict__ b1, const float* __restrict__ b2,
    const float* __restrict__ b3, const float* __restrict__ b4,
    const unsigned short* __restrict__ wf, float* __restrict__ Rout) {
  __shared__ __align__(16) unsigned short wlds[69632];   // 136 frags x 512 u16
  __shared__ __align__(16) float blds[640];              // b1|b2|b3|b4

  const int t = threadIdx.x;
  const int lane = t & 63, w = t >> 6;
  const int cn = lane & 31;         // node-in-tile (B col)
  const int h  = lane >> 5;         // k-group half

  const int g = w * 256 + blockIdx.x;          // wave-slot 0..2047
  const bool active = (g < NT32);
  const int node = (active ? g * 32 : 0) + cn;
  const int nodeL = node < NN ? node : NN - 1;

  // ---- bias global load FIRST (oldest in vmcnt queue)
  f32x4 bval{};
  if (t < 160) {
    const float* s = t < 32 ? b1 + t * 4
                   : t < 64 ? b2 + (t - 32) * 4
                   : t < 96 ? b3 + (t - 64) * 4
                   :          b4 + (t - 96) * 4;
    bval = *(const f32x4*)s;
  }

  // ---- ef/nf loads second
  const float* xp = ef + (size_t)nodeL * 32;
  f32x4 x00 = *(const f32x4*)(xp + h * 8);
  f32x4 x01 = *(const f32x4*)(xp + h * 8 + 4);
  f32x4 x10 = *(const f32x4*)(xp + 16 + h * 8);
  f32x4 x11 = *(const f32x4*)(xp + 16 + h * 8 + 4);
  f32x4 nfa = *(const f32x4*)(nfeat + (size_t)nodeL * 16 + 4 * h);
  f32x4 nfb = *(const f32x4*)(nfeat + (size_t)nodeL * 16 + 8 + 4 * h);

  // ---- 17 DMA rounds, layer-ordered (round i = frags 8i..8i+7)
  {
    const char* gsrc = (const char*)wf;
    char* lbase = (char*)wlds;
    const int soff = w * 1024 + lane * 16;
    const int doff = w * 1024;
    #pragma unroll
    for (int i = 0; i < 17; ++i)
      gl2lds16(gsrc + soff + i * 8192, lbase + doff + i * 8192);
  }
  if (t < 160) ((f32x4*)blds)[t] = bval;   // LDS write (lgkm)

  // ---- gate L1: round 0 (W1) done + bias LDS visible
  asm volatile("s_waitcnt vmcnt(16) lgkmcnt(0)" ::: "memory");
  __builtin_amdgcn_s_barrier();
  __builtin_amdgcn_sched_barrier(0);

  auto initacc = [&](int boff) -> f32x16 {
    f32x16 a;
    #pragma unroll
    for (int q = 0; q < 4; ++q) {
      f32x4 cv = *(const f32x4*)&blds[boff + 4 * h + 8 * q];
      a[4*q+0] = cv[0]; a[4*q+1] = cv[1]; a[4*q+2] = cv[2]; a[4*q+3] = cv[3];
    }
    return a;
  };
  auto frag = [&](int f) -> short8 {
    return *(const short8*)&wlds[f * 512 + lane * 8];
  };

  f32x16 acc[4];
  short8 bf[8];
  auto transition = [&]() {
    #pragma unroll
    for (int s = 0; s < 8; ++s) {
      const f32x16 A = acc[s >> 1];
      const int b0 = 8 * (s & 1);
      u32x4 u = { packbf2(fmaxf(A[b0+0],0.f), fmaxf(A[b0+1],0.f)),
                  packbf2(fmaxf(A[b0+2],0.f), fmaxf(A[b0+3],0.f)),
                  packbf2(fmaxf(A[b0+4],0.f), fmaxf(A[b0+5],0.f)),
                  packbf2(fmaxf(A[b0+6],0.f), fmaxf(A[b0+7],0.f)) };
      bf[s] = __builtin_bit_cast(short8, u);
    }
  };

  // ---- layer 1 (W1 frags 0-7)
  if (active) {
    short8 bx0 = pack8(x00, x01);
    short8 bx1 = pack8(x10, x11);
    #pragma unroll
    for (int ob = 0; ob < 4; ++ob) {
      f32x16 c = initacc(ob * 32);
      c = __builtin_amdgcn_mfma_f32_32x32x16_bf16(frag(ob * 2 + 0), bx0, c, 0, 0, 0);
      c = __builtin_amdgcn_mfma_f32_32x32x16_bf16(frag(ob * 2 + 1), bx1, c, 0, 0, 0);
      acc[ob] = c;
    }
    transition();
  }

  // ---- layers 2 and 3 (rolled; frags 8-39 / 40-71)
  #pragma unroll 1
  for (int L = 0; L < 2; ++L) {
    if (L == 0) asm volatile("s_waitcnt vmcnt(12)" ::: "memory");  // W2 done
    else        asm volatile("s_waitcnt vmcnt(8)"  ::: "memory");  // W3 done
    __builtin_amdgcn_s_barrier();
    __builtin_amdgcn_sched_barrier(0);
    if (active) {
      const int wbase = 8 + L * 32, bbase = 128 + L * 128;
      f32x16 nacc[4];
      #pragma unroll
      for (int ob = 0; ob < 4; ++ob) {
        f32x16 c = initacc(bbase + ob * 32);
        #pragma unroll
        for (int s = 0; s < 8; ++s)
          c = __builtin_amdgcn_mfma_f32_32x32x16_bf16(frag(wbase + ob * 8 + s), bf[s], c, 0, 0, 0);
        nacc[ob] = c;
      }
      acc[0] = nacc[0]; acc[1] = nacc[1]; acc[2] = nacc[2]; acc[3] = nacc[3];
      transition();
    }
  }

  // ---- gate L4: all DMA done (frags 72-135)
  asm volatile("s_waitcnt vmcnt(0)" ::: "memory");
  __builtin_amdgcn_s_barrier();
  __builtin_amdgcn_sched_barrier(0);

  if (!active) return;

  // ---- layer 4 (rolled) + einsum epilogue
  float o0=0.f,o1=0.f,o2=0.f,o3=0.f,o4=0.f,o5=0.f,o6=0.f,o7=0.f;
  #pragma unroll 1
  for (int nb4 = 0; nb4 < 8; ++nb4) {
    f32x16 d = initacc(384 + nb4 * 32);
    #pragma unroll
    for (int s = 0; s < 8; ++s)
      d = __builtin_amdgcn_mfma_f32_32x32x16_bf16(frag(72 + nb4 * 8 + s), bf[s], d, 0, 0, 0);
    float p0 = d[0]*nfa[0] + d[1]*nfa[1] + d[2]*nfa[2] + d[3]*nfa[3]
             + d[4]*nfb[0] + d[5]*nfb[1] + d[6]*nfb[2] + d[7]*nfb[3];
    float p1 = d[8]*nfa[0] + d[9]*nfa[1] + d[10]*nfa[2] + d[11]*nfa[3]
             + d[12]*nfb[0]+ d[13]*nfb[1]+ d[14]*nfb[2]+ d[15]*nfb[3];
    p0 += __shfl_xor(p0, 32, 64);   // combine h-halves (same node)
    p1 += __shfl_xor(p1, 32, 64);
    int rs = nb4 - h * 4;           // lane keeps its h's 4 blocks
    o0 = (rs == 0) ? p0 : o0;  o1 = (rs == 0) ? p1 : o1;
    o2 = (rs == 1) ? p0 : o2;  o3 = (rs == 1) ? p1 : o3;
    o4 = (rs == 2) ? p0 : o4;  o5 = (rs == 2) ? p1 : o5;
    o6 = (rs == 3) ? p0 : o6;  o7 = (rs == 3) ? p1 : o7;
  }
  if (node < NN) {
    f32x4 oa = { o0, o1, o2, o3 };
    f32x4 ob_ = { o4, o5, o6, o7 };
    *(f32x4*)(Rout + (size_t)node * 16 + h * 8)     = oa;
    *(f32x4*)(Rout + (size_t)node * 16 + h * 8 + 4) = ob_;
  }
}

// ---------------------------------------------------------------------------
// Scatter: out[e] = R[edge_index[e,1]] (R6-proven batched form).
// ---------------------------------------------------------------------------
__global__ __launch_bounds__(256) void scatter_kernel(
    const int* __restrict__ eidx, const float* __restrict__ Rbuf,
    float* __restrict__ out) {
  const int tid = blockIdx.x * 256 + threadIdx.x;
  const int total = NE * 4;
  const int i0 = tid;
  const int i1 = tid + SC_THREADS;
  const int i2 = tid + 2 * SC_THREADS;
  const int i3 = tid + 3 * SC_THREADS;
  const bool d3 = (i3 < total);          // i0..i2 always valid

  int nA = eidx[((i0 >> 2) << 1) + 1];
  int nB = eidx[((i1 >> 2) << 1) + 1];
  int nC = eidx[((i2 >> 2) << 1) + 1];
  int nD = d3 ? eidx[((i3 >> 2) << 1) + 1] : 0;

  f32x4 vA = *(const f32x4*)(Rbuf + nA * 16 + (i0 & 3) * 4);
  f32x4 vB = *(const f32x4*)(Rbuf + nB * 16 + (i1 & 3) * 4);
  f32x4 vC = *(const f32x4*)(Rbuf + nC * 16 + (i2 & 3) * 4);
  f32x4 vD = d3 ? *(const f32x4*)(Rbuf + nD * 16 + (i3 & 3) * 4) : f32x4{0,0,0,0};

  *(f32x4*)(out + (size_t)i0 * 4) = vA;
  *(f32x4*)(out + (size_t)i1 * 4) = vB;
  *(f32x4*)(out + (size_t)i2 * 4) = vC;
  if (d3) *(f32x4*)(out + (size_t)i3 * 4) = vD;
}

extern "C" void kernel_launch(void* const* d_in, const int* in_sizes, int n_in,
                              void* d_out, int out_size, void* d_ws, size_t ws_size,
                              hipStream_t stream) {
  const float* ef = (const float*)d_in[0];
  const float* nf = (const float*)d_in[1];
  const float* W1 = (const float*)d_in[2];
  const float* b1 = (const float*)d_in[3];
  const float* W2 = (const float*)d_in[4];
  const float* b2 = (const float*)d_in[5];
  const float* W3 = (const float*)d_in[6];
  const float* b3 = (const float*)d_in[7];
  const float* W4 = (const float*)d_in[8];
  const float* b4 = (const float*)d_in[9];
  const int* eidx = (const int*)d_in[10];

  unsigned short* wfrag = (unsigned short*)d_ws;          // 139264 B bf16 frags
  float* Rbuf = (float*)((char*)d_ws + 139264);           // NN*16 f32 = 3.2 MB
  float* out = (float*)d_out;

  hipLaunchKernelGGL(prep_weights, dim3(34), dim3(256), 0, stream,
                     W1, W2, W3, W4, wfrag);
  hipLaunchKernelGGL(mlp_kernel, dim3(256), dim3(512), 0, stream,
                     ef, nf, b1, b2, b3, b4, wfrag, Rbuf);
  hipLaunchKernelGGL(scatter_kernel, dim3(SC_BLOCKS), dim3(256), 0, stream,
                     eidx, Rbuf, out);
}

// Round 16
// 34.405 us; speedup vs baseline: 1.0519x; 1.0519x over previous
//
#include <hip/hip_runtime.h>
#include <stdint.h>

typedef __attribute__((ext_vector_type(8))) short short8;
typedef __attribute__((ext_vector_type(4))) float f32x4;
typedef __attribute__((ext_vector_type(16))) float f32x16;
typedef __attribute__((ext_vector_type(4))) unsigned int u32x4;

#define NE 500000
#define NN 50000
#define NT32 1563            // ceil(50000/32); last tile has 16 real nodes
#define NROWS 50048          // ef rows actually consumed (NT32*32 rounded up)
#define EF_TASKS 200192      // NROWS*32/8
#define PREP_BLOCKS 816      // 34 (weights) + 782 (ef->bf16)
#define SC_BLOCKS 2048
#define SC_THREADS (SC_BLOCKS * 256)

__device__ __forceinline__ unsigned int f2bf1(float f) {
  unsigned int u = __builtin_bit_cast(unsigned int, f);
  u += 0x7FFFu + ((u >> 16) & 1u);   // round-to-nearest-even
  return u >> 16;
}
__device__ __forceinline__ unsigned int packbf2(float lo, float hi) {
  return f2bf1(lo) | (f2bf1(hi) << 16);
}
__device__ __forceinline__ short8 pack8(f32x4 a, f32x4 b) {
  short8 r;
  r[0] = (short)f2bf1(a[0]); r[1] = (short)f2bf1(a[1]);
  r[2] = (short)f2bf1(a[2]); r[3] = (short)f2bf1(a[3]);
  r[4] = (short)f2bf1(b[0]); r[5] = (short)f2bf1(b[1]);
  r[6] = (short)f2bf1(b[2]); r[7] = (short)f2bf1(b[3]);
  return r;
}

// direct global->LDS DMA, 16B per lane (dest = wave-uniform base + lane*16)
__device__ __forceinline__ void gl2lds16(const void* g, void* l) {
  __builtin_amdgcn_global_load_lds(
      (const __attribute__((address_space(1))) void*)g,
      (__attribute__((address_space(3))) void*)l, 16, 0, 0);
}

// ---------------------------------------------------------------------------
// Prep (two jobs by blockIdx):
//  blocks 0..33  : pack W1..W4 (f32) into kappa-ordered bf16 frags (R10 layout)
//  blocks 34..815: convert ef rows 0..50047 to a bf16 row-major image
//                  (halves the mlp's per-replay cold-read bytes; deletes the
//                   per-wave f2bf pack from the mlp)
// ---------------------------------------------------------------------------
__global__ __launch_bounds__(256) void prep_kernel(
    const float* __restrict__ W1, const float* __restrict__ W2,
    const float* __restrict__ W3, const float* __restrict__ W4,
    const float* __restrict__ ef,
    unsigned short* __restrict__ wf, unsigned short* __restrict__ xb16) {
  if (blockIdx.x >= 34) {
    int j = (blockIdx.x - 34) * 256 + threadIdx.x;   // 8-float task
    if (j < EF_TASKS) {
      const float* s = ef + (size_t)j * 8;
      f32x4 a = *(const f32x4*)s;
      f32x4 b = *(const f32x4*)(s + 4);
      *(short8*)(xb16 + (size_t)j * 8) = pack8(a, b);
    }
    return;
  }
  int idx = blockIdx.x * 256 + threadIdx.x;   // 8704 weight tasks
  if (idx >= 8704) return;
  int f = idx >> 6, l = idx & 63;
  int r = l & 31, hh = l >> 5;
  const float *pa, *pb;
  if (f < 8) {
    int ob = f >> 1, s = f & 1;
    const float* base = W1 + (ob * 32 + r) * 32 + s * 16 + hh * 8;
    pa = base; pb = base + 4;
  } else {
    const float* W; int i2;
    if (f < 40)      { W = W2; i2 = f - 8;  }
    else if (f < 72) { W = W3; i2 = f - 40; }
    else             { W = W4; i2 = f - 72; }
    int ob = i2 >> 3, s = i2 & 7;
    const float* base = W + (ob * 32 + r) * 128
                      + (s >> 1) * 32 + (s & 1) * 16 + 4 * hh;
    pa = base; pb = base + 8;
  }
  *(short8*)&wf[f * 512 + l * 8] = pack8(*(const f32x4*)pa, *(const f32x4*)pb);
}

// ---------------------------------------------------------------------------
// MLP (R14 structure, best measured): 512 thr = 8 waves, one 32-node
// tile/wave, wave-slot g = w*256 + bid. Staging = 17x global_load_lds
// dwordx4 of the pre-packed frag image. B-operand now loads straight from
// the bf16 ef image (2x16B, no VALU pack). nf loads deferred past L3.
// ---------------------------------------------------------------------------
__global__ __launch_bounds__(512, 2) void mlp_kernel(
    const unsigned short* __restrict__ xb16, const float* __restrict__ nfeat,
    const float* __restrict__ b1, const float* __restrict__ b2,
    const float* __restrict__ b3, const float* __restrict__ b4,
    const unsigned short* __restrict__ wf, float* __restrict__ Rout) {
  __shared__ __align__(16) unsigned short wlds[69632];   // 136 frags x 512 u16
  __shared__ __align__(16) float blds[640];              // b1|b2|b3|b4

  const int t = threadIdx.x;
  const int lane = t & 63, w = t >> 6;
  const int cn = lane & 31;         // node-in-tile (B col)
  const int h  = lane >> 5;         // k-group half

  const int g = w * 256 + blockIdx.x;          // wave-slot 0..2047
  const bool active = (g < NT32);
  const int node = (active ? g * 32 : 0) + cn; // < 50016 <= NROWS, xb16 safe
  const int nodeL = node < NN ? node : NN - 1; // clamp for nf; stores predicated

  // B-operand fragments straight from the bf16 image (overlap with DMA below)
  const unsigned short* xr = xb16 + (size_t)node * 32;
  short8 bx0 = *(const short8*)(xr + h * 8);
  short8 bx1 = *(const short8*)(xr + 16 + h * 8);

  // ---- staging: DMA the 139264B fragment image (17 x 8192B rounds)
  {
    const char* gsrc = (const char*)wf;
    char* lbase = (char*)wlds;
    const int soff = w * 1024 + lane * 16;
    const int doff = w * 1024;
    #pragma unroll
    for (int i = 0; i < 17; ++i)
      gl2lds16(gsrc + soff + i * 8192, lbase + doff + i * 8192);
  }
  if (t < 160) {
    const float* s = t < 32 ? b1 + t * 4
                   : t < 64 ? b2 + (t - 32) * 4
                   : t < 96 ? b3 + (t - 64) * 4
                   :          b4 + (t - 96) * 4;
    ((f32x4*)blds)[t] = *(const f32x4*)s;
  }
  __syncthreads();   // drains vmcnt (DMA) + lgkm before use

  if (!active) return;

  // bias init: acc[reg] = b[ob*32 + (reg&3)+8*(reg>>2)+4h]
  auto initacc = [&](int boff) -> f32x16 {
    f32x16 a;
    #pragma unroll
    for (int q = 0; q < 4; ++q) {
      f32x4 cv = *(const f32x4*)&blds[boff + 4 * h + 8 * q];
      a[4*q+0] = cv[0]; a[4*q+1] = cv[1]; a[4*q+2] = cv[2]; a[4*q+3] = cv[3];
    }
    return a;
  };
  auto frag = [&](int f) -> short8 {
    return *(const short8*)&wlds[f * 512 + lane * 8];
  };

  // ---- layer 1: 4 out-blocks x 2 k-steps
  f32x16 acc[4];
  #pragma unroll
  for (int ob = 0; ob < 4; ++ob) {
    f32x16 c = initacc(ob * 32);
    c = __builtin_amdgcn_mfma_f32_32x32x16_bf16(frag(ob * 2 + 0), bx0, c, 0, 0, 0);
    c = __builtin_amdgcn_mfma_f32_32x32x16_bf16(frag(ob * 2 + 1), bx1, c, 0, 0, 0);
    acc[ob] = c;
  }

  // ReLU + repack acc -> next-layer B-fragments (pure registers)
  short8 bf[8];
  auto transition = [&]() {
    #pragma unroll
    for (int s = 0; s < 8; ++s) {
      const f32x16 A = acc[s >> 1];
      const int b0 = 8 * (s & 1);
      u32x4 u = { packbf2(fmaxf(A[b0+0],0.f), fmaxf(A[b0+1],0.f)),
                  packbf2(fmaxf(A[b0+2],0.f), fmaxf(A[b0+3],0.f)),
                  packbf2(fmaxf(A[b0+4],0.f), fmaxf(A[b0+5],0.f)),
                  packbf2(fmaxf(A[b0+6],0.f), fmaxf(A[b0+7],0.f)) };
      bf[s] = __builtin_bit_cast(short8, u);
    }
  };
  transition();

  // ---- layers 2 and 3: 4 out-blocks x 8 k-steps each
  #pragma unroll
  for (int L = 0; L < 2; ++L) {
    const int wbase = 8 + L * 32, bbase = 128 + L * 128;
    f32x16 nacc[4];
    #pragma unroll
    for (int ob = 0; ob < 4; ++ob) {
      f32x16 c = initacc(bbase + ob * 32);
      #pragma unroll
      for (int s = 0; s < 8; ++s)
        c = __builtin_amdgcn_mfma_f32_32x32x16_bf16(frag(wbase + ob * 8 + s), bf[s], c, 0, 0, 0);
      nacc[ob] = c;
    }
    acc[0] = nacc[0]; acc[1] = nacc[1]; acc[2] = nacc[2]; acc[3] = nacc[3];
    transition();
  }

  // nf loads deferred to here: latency hides under layer 4's MFMA chains
  f32x4 nfa = *(const f32x4*)(nfeat + (size_t)nodeL * 16 + 4 * h);
  f32x4 nfb = *(const f32x4*)(nfeat + (size_t)nodeL * 16 + 8 + 4 * h);

  // ---- layer 4 (8 out-blocks) + einsum epilogue
  float o0=0.f,o1=0.f,o2=0.f,o3=0.f,o4=0.f,o5=0.f,o6=0.f,o7=0.f;
  #pragma unroll
  for (int nb4 = 0; nb4 < 8; ++nb4) {
    f32x16 d = initacc(384 + nb4 * 32);
    #pragma unroll
    for (int s = 0; s < 8; ++s)
      d = __builtin_amdgcn_mfma_f32_32x32x16_bf16(frag(72 + nb4 * 8 + s), bf[s], d, 0, 0, 0);
    float p0 = d[0]*nfa[0] + d[1]*nfa[1] + d[2]*nfa[2] + d[3]*nfa[3]
             + d[4]*nfb[0] + d[5]*nfb[1] + d[6]*nfb[2] + d[7]*nfb[3];
    float p1 = d[8]*nfa[0] + d[9]*nfa[1] + d[10]*nfa[2] + d[11]*nfa[3]
             + d[12]*nfb[0]+ d[13]*nfb[1]+ d[14]*nfb[2]+ d[15]*nfb[3];
    p0 += __shfl_xor(p0, 32, 64);   // combine h-halves (same node)
    p1 += __shfl_xor(p1, 32, 64);
    int rs = nb4 - h * 4;           // lane keeps its h's 4 blocks
    o0 = (rs == 0) ? p0 : o0;  o1 = (rs == 0) ? p1 : o1;
    o2 = (rs == 1) ? p0 : o2;  o3 = (rs == 1) ? p1 : o3;
    o4 = (rs == 2) ? p0 : o4;  o5 = (rs == 2) ? p1 : o5;
    o6 = (rs == 3) ? p0 : o6;  o7 = (rs == 3) ? p1 : o7;
  }
  if (node < NN) {
    f32x4 oa = { o0, o1, o2, o3 };
    f32x4 ob_ = { o4, o5, o6, o7 };
    *(f32x4*)(Rout + (size_t)node * 16 + h * 8)     = oa;
    *(f32x4*)(Rout + (size_t)node * 16 + h * 8 + 4) = ob_;
  }
}

// ---------------------------------------------------------------------------
// Scatter: out[e] = R[edge_index[e,1]] (R6-proven batched form).
// ---------------------------------------------------------------------------
__global__ __launch_bounds__(256) void scatter_kernel(
    const int* __restrict__ eidx, const float* __restrict__ Rbuf,
    float* __restrict__ out) {
  const int tid = blockIdx.x * 256 + threadIdx.x;
  const int total = NE * 4;
  const int i0 = tid;
  const int i1 = tid + SC_THREADS;
  const int i2 = tid + 2 * SC_THREADS;
  const int i3 = tid + 3 * SC_THREADS;
  const bool d3 = (i3 < total);          // i0..i2 always valid

  int nA = eidx[((i0 >> 2) << 1) + 1];
  int nB = eidx[((i1 >> 2) << 1) + 1];
  int nC = eidx[((i2 >> 2) << 1) + 1];
  int nD = d3 ? eidx[((i3 >> 2) << 1) + 1] : 0;

  f32x4 vA = *(const f32x4*)(Rbuf + nA * 16 + (i0 & 3) * 4);
  f32x4 vB = *(const f32x4*)(Rbuf + nB * 16 + (i1 & 3) * 4);
  f32x4 vC = *(const f32x4*)(Rbuf + nC * 16 + (i2 & 3) * 4);
  f32x4 vD = d3 ? *(const f32x4*)(Rbuf + nD * 16 + (i3 & 3) * 4) : f32x4{0,0,0,0};

  *(f32x4*)(out + (size_t)i0 * 4) = vA;
  *(f32x4*)(out + (size_t)i1 * 4) = vB;
  *(f32x4*)(out + (size_t)i2 * 4) = vC;
  if (d3) *(f32x4*)(out + (size_t)i3 * 4) = vD;
}

extern "C" void kernel_launch(void* const* d_in, const int* in_sizes, int n_in,
                              void* d_out, int out_size, void* d_ws, size_t ws_size,
                              hipStream_t stream) {
  const float* ef = (const float*)d_in[0];
  const float* nf = (const float*)d_in[1];
  const float* W1 = (const float*)d_in[2];
  const float* b1 = (const float*)d_in[3];
  const float* W2 = (const float*)d_in[4];
  const float* b2 = (const float*)d_in[5];
  const float* W3 = (const float*)d_in[6];
  const float* b3 = (const float*)d_in[7];
  const float* W4 = (const float*)d_in[8];
  const float* b4 = (const float*)d_in[9];
  const int* eidx = (const int*)d_in[10];

  unsigned short* wfrag = (unsigned short*)d_ws;          // 139264 B bf16 frags
  float* Rbuf = (float*)((char*)d_ws + 139264);           // NN*16 f32 = 3.2 MB
  unsigned short* xb16 = (unsigned short*)((char*)d_ws + 139264 + 3200000);
  float* out = (float*)d_out;

  hipLaunchKernelGGL(prep_kernel, dim3(PREP_BLOCKS), dim3(256), 0, stream,
                     W1, W2, W3, W4, ef, wfrag, xb16);
  hipLaunchKernelGGL(mlp_kernel, dim3(256), dim3(512), 0, stream,
                     xb16, nf, b1, b2, b3, b4, wfrag, Rbuf);
  hipLaunchKernelGGL(scatter_kernel, dim3(SC_BLOCKS), dim3(256), 0, stream,
                     eidx, Rbuf, out);
}